// Round 5
// baseline (237.121 us; speedup 1.0000x reference)
//
#include <hip/hip_runtime.h>

#define NB 64
#define ZDIM 128
#define NCOEF 1025
#define NFR 128
#define COLS 131200          /* NCOEF*NFR */
#define WINSZ 2048
#define HALFW 1024
#define NSAMP 131072
#define IMPN 4096
#define NCHUNK 16            /* chunks of 8 spans */

// workspace layout in floats
#define TF_OFF   0
#define TF_SZ    (NB*COLS)
#define CUR_OFF  (TF_OFF + TF_SZ)
#define CUR_SZ   (NB*4*NCOEF*2)
#define CK_OFF   (CUR_OFF + CUR_SZ)
#define CK_SZ    (15*NB*NCOEF*2)
#define WINT_OFF (CK_OFF + CK_SZ)
#define WINT_SZ  (WINSZ)
#define TW_OFF   (WINT_OFF + WINT_SZ)
#define TW_SZ    (HALFW*2)

#define PHYS(i) ((i) ^ (((i) >> 5) & 3))

typedef short bf16x8 __attribute__((ext_vector_type(8)));
typedef float f32x4 __attribute__((ext_vector_type(4)));

// ---------------------------------------------------------------- init tables
__global__ __launch_bounds__(256) void init_tables(float* __restrict__ winT,
                                                   float2* __restrict__ twG) {
  int i = blockIdx.x * 256 + threadIdx.x;
  if (i < WINSZ) {
    winT[i] = 0.5f - 0.5f * cosf((float)(2.0 * 3.14159265358979323846 / 2048.0) * (float)i);
  }
  if (i < HALFW) {
    float ang = (float)(-2.0 * 3.14159265358979323846 / 2048.0) * (float)i;
    float sv, cv;
    sincosf(ang, &sv, &cv);
    twG[i] = make_float2(cv, sv);
  }
}

// ---------------------------------------------------------------- MFMA GEMM + squash
__device__ __forceinline__ short f2bf(float f) {
  unsigned u = __builtin_bit_cast(unsigned, f);
  u += 0x7FFFu + ((u >> 16) & 1u);      // RNE
  return (short)(u >> 16);
}

__global__ __launch_bounds__(256) void tf_gemm_mfma(const float* __restrict__ z,
                                                    const float* __restrict__ W,
                                                    const float* __restrict__ bias,
                                                    float* __restrict__ tf) {
  int tid = threadIdx.x;
  int wave = tid >> 6, lane = tid & 63;
  int colw = blockIdx.x * 128 + wave * 32;
  int lr = lane & 15;
  int lk = (lane >> 4) * 8;
  int lq = (lane >> 4) * 4;

  float bv[2];
#pragma unroll
  for (int n = 0; n < 2; ++n) bv[n] = bias[colw + 16 * n + lr];

  f32x4 acc[4][2];
#pragma unroll
  for (int m = 0; m < 4; ++m)
#pragma unroll
    for (int n = 0; n < 2; ++n)
      acc[m][n] = f32x4{bv[n], bv[n], bv[n], bv[n]};

#pragma unroll
  for (int s = 0; s < 4; ++s) {
    int k0 = s * 32 + lk;
    bf16x8 afr[4];
#pragma unroll
    for (int m = 0; m < 4; ++m) {
      const float* zp = z + (size_t)(16 * m + lr) * ZDIM + k0;
      float4 z0 = *reinterpret_cast<const float4*>(zp);
      float4 z1 = *reinterpret_cast<const float4*>(zp + 4);
      afr[m] = bf16x8{f2bf(z0.x), f2bf(z0.y), f2bf(z0.z), f2bf(z0.w),
                      f2bf(z1.x), f2bf(z1.y), f2bf(z1.z), f2bf(z1.w)};
    }
    bf16x8 bfr[2];
#pragma unroll
    for (int n = 0; n < 2; ++n) {
      const float* wp = W + (size_t)k0 * COLS + colw + 16 * n + lr;
      bfr[n] = bf16x8{f2bf(wp[0 * (size_t)COLS]), f2bf(wp[1 * (size_t)COLS]),
                      f2bf(wp[2 * (size_t)COLS]), f2bf(wp[3 * (size_t)COLS]),
                      f2bf(wp[4 * (size_t)COLS]), f2bf(wp[5 * (size_t)COLS]),
                      f2bf(wp[6 * (size_t)COLS]), f2bf(wp[7 * (size_t)COLS])};
    }
#pragma unroll
    for (int m = 0; m < 4; ++m)
#pragma unroll
      for (int n = 0; n < 2; ++n)
        acc[m][n] = __builtin_amdgcn_mfma_f32_16x16x32_bf16(afr[m], bfr[n], acc[m][n], 0, 0, 0);
  }

  const float RESR = (1.0f - 0.02f) * 0.99f;
#pragma unroll
  for (int n = 0; n < 2; ++n) {
    int col = colw + 16 * n + lr;
#pragma unroll
    for (int m = 0; m < 4; ++m) {
      int rowb = 16 * m + lq;
#pragma unroll
      for (int r = 0; r < 4; ++r) {
        float x = acc[m][n][r];
        float sg = 1.0f / (1.0f + __expf(-x));
        tf[(size_t)(rowb + r) * COLS + col] = 0.02f + sg * RESR;
      }
    }
  }
}

// ---------------------------------------------------------------- fwd 2048 FFT (radix-2)
static __device__ __forceinline__ void wg_fft2048(float* ar, float* ai,
                                                  float* br, float* bi,
                                                  const float2* tw,
                                                  float** outr, float** outi) {
  float *xr = ar, *xi = ai, *yr = br, *yi = bi;
  int m = 1;
  for (int s = 0; s < 11; ++s) {
    __syncthreads();
#pragma unroll
    for (int it = 0; it < 4; ++it) {
      int t = (int)threadIdx.x + it * 256;
      int jm = t & ~(m - 1);
      float x0r = xr[t], x0i = xi[t];
      float x1r = xr[t + 1024], x1i = xi[t + 1024];
      float2 w = tw[jm];
      float sr = x0r + x1r, si = x0i + x1i;
      float dr = x0r - x1r, di = x0i - x1i;
      float pr = dr * w.x - di * w.y;
      float pi = dr * w.y + di * w.x;
      yr[t + jm] = sr;      yi[t + jm] = si;
      yr[t + jm + m] = pr;  yi[t + jm + m] = pi;
    }
    float* t0 = xr; xr = yr; yr = t0;
    float* t1 = xi; xi = yi; yi = t1;
    m <<= 1;
  }
  __syncthreads();
  *outr = xr; *outi = xi;
}

__global__ __launch_bounds__(256) void fwd_fft_kernel(const float* __restrict__ imp,
                                                      const float* __restrict__ winT,
                                                      const float2* __restrict__ twG,
                                                      float2* __restrict__ cur) {
  __shared__ float b0r[WINSZ], b0i[WINSZ], b1r[WINSZ], b1i[WINSZ];
  __shared__ float2 tw[HALFW];
  int wg = blockIdx.x;
  int b = wg >> 2, f = wg & 3;
  int tid = threadIdx.x;

  for (int i = tid; i < HALFW; i += 256) tw[i] = twG[i];
  for (int w = tid; w < WINSZ; w += 256) {
    int s = f * HALFW + w;
    float v = (s < IMPN) ? imp[(size_t)b * IMPN + s] * winT[w] : 0.0f;
    b0r[w] = v;
    b0i[w] = 0.0f;
  }
  float *rr, *ri;
  wg_fft2048(b0r, b0i, b1r, b1i, tw, &rr, &ri);
  for (int k = tid; k < NCOEF; k += 256)
    cur[(size_t)wg * NCOEF + k] = make_float2(rr[k], ri[k]);
}

// ---------------------------------------------------------------- recurrence checkpoints
// Same chain as before, but stores only state after frames 6,14,...,118.
__global__ __launch_bounds__(256) void recur_ck(const float* __restrict__ tf,
                                                const float2* __restrict__ cur,
                                                float2* __restrict__ ckp) {
  int id = blockIdx.x * 256 + threadIdx.x;
  if (id >= NB * NCOEF) return;
  int b = id / NCOEF;
  int k = id - b * NCOEF;

  float g = 3.14159265358979323846f * (float)k / 1024.0f;
  float sg, cg;
  sincosf(g, &sg, &cg);
  bool herm = (k == 0) || (k == HALFW);

  const float4* tf4 = (const float4*)(tf + (size_t)b * COLS + (size_t)k * NFR);
  const float2* curb = cur + (size_t)b * 4 * NCOEF + k;

  float pre = 0.0f, pim = 0.0f;
  for (int f4 = 0; f4 < 30; ++f4) {       // frames 0..119 (last ck at 118)
    float4 tv = tf4[f4];
    float tfs[4] = {tv.x, tv.y, tv.z, tv.w};
#pragma unroll
    for (int u = 0; u < 4; ++u) {
      int f = 4 * f4 + u;
      float tfv = tfs[u];
      float cr = 0.0f, ci = 0.0f;
      if (f < 4) {
        float2 cv = curb[(size_t)f * NCOEF];
        cr = cv.x; ci = cv.y;
      }
      float ire = herm ? 0.0f : pim;
      float rre = fmaf(pre, cg, ire * sg);
      float rim = -fmaf(pre, sg, ire * cg);
      float sre = (cr + rre) * tfv;
      float sim = (ci + rim) * tfv;
      if ((f & 7) == 6)
        ckp[(size_t)((f - 6) >> 3) * NB * NCOEF + (size_t)b * NCOEF + k] = make_float2(sre, sim);
      pre = sre; pim = sim;
    }
  }
}

// ---------------------------------------------------------------- fused recur + irfft + OLA
// Block (b, c): spans [8c, 8c+8). Computes frames fs..8c+7 (fs = 0 or 8c-1),
// restarting the spectral recurrence from checkpoint c-1. Each frame:
// state advance (regs) -> X to LDS -> pack -> radix-4 FFT1024 -> windowed
// extract; second half carried in registers to the next span. No atomics.
__global__ __launch_bounds__(256) void fused_resyn(const float* __restrict__ tf,
                                                   const float2* __restrict__ cur,
                                                   const float2* __restrict__ ckp,
                                                   const float* __restrict__ winT,
                                                   const float2* __restrict__ twG,
                                                   float* __restrict__ out) {
  __shared__ float L0r[1024], L0i[1024], L1r[1024], L1i[1024];
  __shared__ float2 twL[256];

  int bidx = blockIdx.x;
  int b = bidx >> 4, c = bidx & 15;
  int tid = threadIdx.x;

  twL[tid] = twG[2 * tid];

  // recurrence slots: k = tid + 256*i (i<4); thread 0 also owns k=1024 (i=4)
  float pre[5], pim[5], cgv[5], sgv[5];
#pragma unroll
  for (int i = 0; i < 5; ++i) {
    if (i == 4) { cgv[4] = -1.0f; sgv[4] = 0.0f; }
    else {
      float2 tv = twG[tid + 256 * i];
      cgv[i] = tv.x; sgv[i] = -tv.y;       // cos/sin(pi*k/1024)
    }
    pre[i] = 0.0f; pim[i] = 0.0f;
  }
  if (c > 0) {
    const float2* ck = ckp + ((size_t)(c - 1) * NB + b) * NCOEF;
#pragma unroll
    for (int i = 0; i < 5; ++i) {
      if (i == 4 && tid != 0) continue;
      int k = (i == 4) ? 1024 : tid + 256 * i;
      float2 v = ck[k];
      pre[i] = v.x; pim[i] = v.y;
    }
  }

  int fs = (c == 0) ? 0 : 8 * c - 1;
  int fe2 = 8 * c + 7;
  float ce0 = 0.0f, co0 = 0.0f, ce1 = 0.0f, co1 = 0.0f;   // carry (2nd half)
  const float* tfb = tf + (size_t)b * COLS;
  const float2* curb = cur + (size_t)b * 4 * NCOEF;
  const float2* win2 = (const float2*)winT;
  const float scale = 1.0f / 1024.0f;
  __syncthreads();   // twL ready

  for (int f = fs; f <= fe2; ++f) {
    // ---- advance recurrence (registers)
    float sreg[5], simg[5];
#pragma unroll
    for (int i = 0; i < 5; ++i) {
      if (i == 4 && tid != 0) { sreg[4] = 0.0f; simg[4] = 0.0f; continue; }
      int k = (i == 4) ? 1024 : tid + 256 * i;
      float tfv = tfb[(size_t)k * NFR + f];
      float cr = 0.0f, ci = 0.0f;
      if (f < 4) {
        float2 cv = curb[(size_t)f * NCOEF + k];
        cr = cv.x; ci = cv.y;
      }
      float rre = fmaf(pre[i], cgv[i], pim[i] * sgv[i]);
      float rim = -fmaf(pre[i], sgv[i], pim[i] * cgv[i]);
      float sre = (cr + rre) * tfv;
      float sim = (ci + rim) * tfv;
      sreg[i] = sre; simg[i] = sim;
      pre[i] = sre; pim[i] = sim;
    }
    __syncthreads();                 // prev extract done; L1 free
    // ---- X into pong planes (L1)
#pragma unroll
    for (int i = 0; i < 4; ++i) {
      int pk = PHYS(tid + 256 * i);
      L1r[pk] = sreg[i]; L1i[pk] = simg[i];
    }
    __syncthreads();
    // ---- pack Z (conj) into ping planes (L0)
#pragma unroll
    for (int it = 0; it < 4; ++it) {
      int j = tid + it * 256;
      float2 tg = twG[j];
      float cc = tg.x, sn = -tg.y;
      int pj = PHYS(j);
      float xjr = L1r[pj], xji = L1i[pj];
      float xmr, xmi;
      if (j == 0) { xmr = sreg[4]; xmi = 0.0f; }    // Nyquist (tid 0 only)
      else { int pm = PHYS(1024 - j); xmr = L1r[pm]; xmi = L1i[pm]; }
      float Xer = 0.5f * (xjr + xmr), Xei = 0.5f * (xji - xmi);
      float Xpr = 0.5f * (xjr - xmr), Xpi = 0.5f * (xji + xmi);
      float Xor_ = Xpr * cc - Xpi * sn;
      float Xoi_ = Xpr * sn + Xpi * cc;
      L0r[pj] = Xer - Xoi_;
      L0i[pj] = -(Xei + Xor_);
    }
    // ---- radix-4 Stockham, 5 stages; even st: L0->L1, odd: L1->L0
    int t = tid;
#pragma unroll
    for (int st = 0; st < 5; ++st) {
      __syncthreads();
      int s = 1 << (2 * st);
      int q = t & (s - 1);
      int j = t & ~(s - 1);
      float2 w1 = twL[j];
      float w1x = w1.x, w1y = w1.y;
      float w2x = w1x * w1x - w1y * w1y, w2y = 2.0f * w1x * w1y;
      float w3x = w2x * w1x - w2y * w1y, w3y = w2x * w1y + w2y * w1x;
      int i0 = PHYS(t), i1 = PHYS(t + 256), i2 = PHYS(t + 512), i3 = PHYS(t + 768);
      int wb = (j << 2) + q;
      int o0 = PHYS(wb), o1 = PHYS(wb + s), o2 = PHYS(wb + 2 * s), o3 = PHYS(wb + 3 * s);
      const float *xr, *xi;
      float *yr, *yi;
      if (st & 1) { xr = L1r; xi = L1i; yr = L0r; yi = L0i; }
      else        { xr = L0r; xi = L0i; yr = L1r; yi = L1i; }
      float ar_ = xr[i0], ai_ = xi[i0];
      float br_ = xr[i1], bi_ = xi[i1];
      float cr_ = xr[i2], ci_ = xi[i2];
      float dr_ = xr[i3], di_ = xi[i3];
      float apcr = ar_ + cr_, apci = ai_ + ci_;
      float amcr = ar_ - cr_, amci = ai_ - ci_;
      float bpdr = br_ + dr_, bpdi = bi_ + di_;
      float bmdr = br_ - dr_, bmdi = bi_ - di_;
      yr[o0] = apcr + bpdr;             yi[o0] = apci + bpdi;
      float t1r = amcr + bmdi, t1i = amci - bmdr;
      yr[o1] = t1r * w1x - t1i * w1y;   yi[o1] = t1r * w1y + t1i * w1x;
      float t2r = apcr - bpdr, t2i = apci - bpdi;
      yr[o2] = t2r * w2x - t2i * w2y;   yi[o2] = t2r * w2y + t2i * w2x;
      float t3r = amcr - bmdi, t3i = amci + bmdr;
      yr[o3] = t3r * w3x - t3i * w3y;   yi[o3] = t3r * w3y + t3i * w3x;
    }
    __syncthreads();
    // result in L1 (stage 4 even). x[2m]=Re z[m]/1024, x[2m+1]=-Im z[m]/1024.
    // ---- extract: span f = first half + carried second half of f-1
#pragma unroll
    for (int it = 0; it < 2; ++it) {
      int mI = tid + it * 256;
      float2 wa = win2[mI];
      float2 wb2 = win2[mI + 512];
      int pa = PHYS(mI), pb = PHYS(mI + 512);
      float fe_ = L1r[pa] * scale * wa.x;
      float fo_ = -L1i[pa] * scale * wa.y;
      float se_ = L1r[pb] * scale * wb2.x;
      float so_ = -L1i[pb] * scale * wb2.y;
      if (f >= 8 * c) {
        float2* ob = (float2*)(out + (size_t)b * NSAMP + (size_t)f * 1024);
        float pce = it ? ce1 : ce0, pco = it ? co1 : co0;
        ob[mI] = make_float2(fe_ + pce, fo_ + pco);
      }
      if (it) { ce1 = se_; co1 = so_; } else { ce0 = se_; co0 = so_; }
    }
  }
}

// ---------------------------------------------------------------- launch
extern "C" void kernel_launch(void* const* d_in, const int* in_sizes, int n_in,
                              void* d_out, int out_size, void* d_ws, size_t ws_size,
                              hipStream_t stream) {
  const float* z    = (const float*)d_in[0];
  const float* imp  = (const float*)d_in[1];
  const float* W    = (const float*)d_in[2];
  const float* bias = (const float*)d_in[3];

  float* ws = (float*)d_ws;
  float*  tf   = ws + TF_OFF;
  float2* cur  = (float2*)(ws + CUR_OFF);
  float2* ckp  = (float2*)(ws + CK_OFF);
  float*  winT = ws + WINT_OFF;
  float2* twG  = (float2*)(ws + TW_OFF);
  float*  out  = (float*)d_out;

  init_tables<<<8, 256, 0, stream>>>(winT, twG);
  tf_gemm_mfma<<<COLS / 128, 256, 0, stream>>>(z, W, bias, tf);
  fwd_fft_kernel<<<NB * 4, 256, 0, stream>>>(imp, winT, twG, cur);
  recur_ck<<<(NB * NCOEF + 255) / 256, 256, 0, stream>>>(tf, cur, ckp);
  fused_resyn<<<NB * NCHUNK, 256, 0, stream>>>(tf, cur, ckp, winT, twG, out);
}

// Round 6
// 104.505 us; speedup vs baseline: 2.2690x; 2.2690x over previous
//
#include <hip/hip_runtime.h>

#define NB 64
#define ZDIM 128
#define NCOEF 1025
#define NFR 128
#define COLS 131200          /* NCOEF*NFR */
#define WINSZ 2048
#define HALFW 1024
#define NSAMP 131072
#define IMPN 4096
#define NCHUNK 32            /* chunks of 4 spans */
#define NCK 31               /* checkpoints: after frames 2,6,...,122 */

// workspace layout in floats
#define TF_OFF   0
#define TF_SZ    (NB*COLS)
#define TFT_OFF  (TF_OFF + TF_SZ)
#define TFT_SZ   (NB*NFR*NCOEF)
#define CUR_OFF  (TFT_OFF + TFT_SZ)
#define CUR_SZ   (NB*4*NCOEF*2)
#define CK_OFF   (CUR_OFF + CUR_SZ)
#define CK_SZ    (NCK*NB*NCOEF*2)
#define WINT_OFF (CK_OFF + CK_SZ)
#define WINT_SZ  (WINSZ)
#define TW_OFF   (WINT_OFF + WINT_SZ)
#define TW_SZ    (HALFW*2)

#define PHYS(i) ((i) ^ (((i) >> 5) & 3))

typedef short bf16x8 __attribute__((ext_vector_type(8)));
typedef float f32x4 __attribute__((ext_vector_type(4)));

// ---------------------------------------------------------------- init tables
__global__ __launch_bounds__(256) void init_tables(float* __restrict__ winT,
                                                   float2* __restrict__ twG) {
  int i = blockIdx.x * 256 + threadIdx.x;
  if (i < WINSZ) {
    winT[i] = 0.5f - 0.5f * cosf((float)(2.0 * 3.14159265358979323846 / 2048.0) * (float)i);
  }
  if (i < HALFW) {
    float ang = (float)(-2.0 * 3.14159265358979323846 / 2048.0) * (float)i;
    float sv, cv;
    sincosf(ang, &sv, &cv);
    twG[i] = make_float2(cv, sv);
  }
}

// ---------------------------------------------------------------- MFMA GEMM + squash
__device__ __forceinline__ short f2bf(float f) {
  unsigned u = __builtin_bit_cast(unsigned, f);
  u += 0x7FFFu + ((u >> 16) & 1u);      // RNE
  return (short)(u >> 16);
}

__global__ __launch_bounds__(256) void tf_gemm_mfma(const float* __restrict__ z,
                                                    const float* __restrict__ W,
                                                    const float* __restrict__ bias,
                                                    float* __restrict__ tf) {
  int tid = threadIdx.x;
  int wave = tid >> 6, lane = tid & 63;
  int colw = blockIdx.x * 128 + wave * 32;
  int lr = lane & 15;
  int lk = (lane >> 4) * 8;
  int lq = (lane >> 4) * 4;

  float bv[2];
#pragma unroll
  for (int n = 0; n < 2; ++n) bv[n] = bias[colw + 16 * n + lr];

  f32x4 acc[4][2];
#pragma unroll
  for (int m = 0; m < 4; ++m)
#pragma unroll
    for (int n = 0; n < 2; ++n)
      acc[m][n] = f32x4{bv[n], bv[n], bv[n], bv[n]};

#pragma unroll
  for (int s = 0; s < 4; ++s) {
    int k0 = s * 32 + lk;
    bf16x8 afr[4];
#pragma unroll
    for (int m = 0; m < 4; ++m) {
      const float* zp = z + (size_t)(16 * m + lr) * ZDIM + k0;
      float4 z0 = *reinterpret_cast<const float4*>(zp);
      float4 z1 = *reinterpret_cast<const float4*>(zp + 4);
      afr[m] = bf16x8{f2bf(z0.x), f2bf(z0.y), f2bf(z0.z), f2bf(z0.w),
                      f2bf(z1.x), f2bf(z1.y), f2bf(z1.z), f2bf(z1.w)};
    }
    bf16x8 bfr[2];
#pragma unroll
    for (int n = 0; n < 2; ++n) {
      const float* wp = W + (size_t)k0 * COLS + colw + 16 * n + lr;
      bfr[n] = bf16x8{f2bf(wp[0 * (size_t)COLS]), f2bf(wp[1 * (size_t)COLS]),
                      f2bf(wp[2 * (size_t)COLS]), f2bf(wp[3 * (size_t)COLS]),
                      f2bf(wp[4 * (size_t)COLS]), f2bf(wp[5 * (size_t)COLS]),
                      f2bf(wp[6 * (size_t)COLS]), f2bf(wp[7 * (size_t)COLS])};
    }
#pragma unroll
    for (int m = 0; m < 4; ++m)
#pragma unroll
      for (int n = 0; n < 2; ++n)
        acc[m][n] = __builtin_amdgcn_mfma_f32_16x16x32_bf16(afr[m], bfr[n], acc[m][n], 0, 0, 0);
  }

  const float RESR = (1.0f - 0.02f) * 0.99f;
#pragma unroll
  for (int n = 0; n < 2; ++n) {
    int col = colw + 16 * n + lr;
#pragma unroll
    for (int m = 0; m < 4; ++m) {
      int rowb = 16 * m + lq;
#pragma unroll
      for (int r = 0; r < 4; ++r) {
        float x = acc[m][n][r];
        float sg = 1.0f / (1.0f + __expf(-x));
        tf[(size_t)(rowb + r) * COLS + col] = 0.02f + sg * RESR;
      }
    }
  }
}

// ---------------------------------------------------------------- fwd 2048 FFT (radix-2)
static __device__ __forceinline__ void wg_fft2048(float* ar, float* ai,
                                                  float* br, float* bi,
                                                  const float2* tw,
                                                  float** outr, float** outi) {
  float *xr = ar, *xi = ai, *yr = br, *yi = bi;
  int m = 1;
  for (int s = 0; s < 11; ++s) {
    __syncthreads();
#pragma unroll
    for (int it = 0; it < 4; ++it) {
      int t = (int)threadIdx.x + it * 256;
      int jm = t & ~(m - 1);
      float x0r = xr[t], x0i = xi[t];
      float x1r = xr[t + 1024], x1i = xi[t + 1024];
      float2 w = tw[jm];
      float sr = x0r + x1r, si = x0i + x1i;
      float dr = x0r - x1r, di = x0i - x1i;
      float pr = dr * w.x - di * w.y;
      float pi = dr * w.y + di * w.x;
      yr[t + jm] = sr;      yi[t + jm] = si;
      yr[t + jm + m] = pr;  yi[t + jm + m] = pi;
    }
    float* t0 = xr; xr = yr; yr = t0;
    float* t1 = xi; xi = yi; yi = t1;
    m <<= 1;
  }
  __syncthreads();
  *outr = xr; *outi = xi;
}

__global__ __launch_bounds__(256) void fwd_fft_kernel(const float* __restrict__ imp,
                                                      const float* __restrict__ winT,
                                                      const float2* __restrict__ twG,
                                                      float2* __restrict__ cur) {
  __shared__ float b0r[WINSZ], b0i[WINSZ], b1r[WINSZ], b1i[WINSZ];
  __shared__ float2 tw[HALFW];
  int wg = blockIdx.x;
  int b = wg >> 2, f = wg & 3;
  int tid = threadIdx.x;

  for (int i = tid; i < HALFW; i += 256) tw[i] = twG[i];
  for (int w = tid; w < WINSZ; w += 256) {
    int s = f * HALFW + w;
    float v = (s < IMPN) ? imp[(size_t)b * IMPN + s] * winT[w] : 0.0f;
    b0r[w] = v;
    b0i[w] = 0.0f;
  }
  float *rr, *ri;
  wg_fft2048(b0r, b0i, b1r, b1i, tw, &rr, &ri);
  for (int k = tid; k < NCOEF; k += 256)
    cur[(size_t)wg * NCOEF + k] = make_float2(rr[k], ri[k]);
}

// ---------------------------------------------------------------- recurrence checkpoints + tf transpose
// Stores state after frames 2,6,...,122 (31 ckpts) AND writes tft[b][f][k]
// (f-major transpose of tf) with coalesced stores for the fused consumer.
__global__ __launch_bounds__(256) void recur_ck_t(const float* __restrict__ tf,
                                                  const float2* __restrict__ cur,
                                                  float2* __restrict__ ckp,
                                                  float* __restrict__ tft) {
  int id = blockIdx.x * 256 + threadIdx.x;
  if (id >= NB * NCOEF) return;
  int b = id / NCOEF;
  int k = id - b * NCOEF;

  float g = 3.14159265358979323846f * (float)k / 1024.0f;
  float sg, cg;
  sincosf(g, &sg, &cg);
  bool herm = (k == 0) || (k == HALFW);

  const float4* tf4 = (const float4*)(tf + (size_t)b * COLS + (size_t)k * NFR);
  const float2* curb = cur + (size_t)b * 4 * NCOEF + k;
  float* tftb = tft + (size_t)b * NFR * NCOEF + k;

  float pre = 0.0f, pim = 0.0f;
  for (int f4 = 0; f4 < 32; ++f4) {
    float4 tv = tf4[f4];
    float tfs[4] = {tv.x, tv.y, tv.z, tv.w};
#pragma unroll
    for (int u = 0; u < 4; ++u) {
      int f = 4 * f4 + u;
      tftb[(size_t)f * NCOEF] = tfs[u];       // coalesced transpose write
      if (f < 124) {                           // recurrence needed thru f=122
        float tfv = tfs[u];
        float cr = 0.0f, ci = 0.0f;
        if (f < 4) {
          float2 cv = curb[(size_t)f * NCOEF];
          cr = cv.x; ci = cv.y;
        }
        float ire = herm ? 0.0f : pim;
        float rre = fmaf(pre, cg, ire * sg);
        float rim = -fmaf(pre, sg, ire * cg);
        float sre = (cr + rre) * tfv;
        float sim = (ci + rim) * tfv;
        if ((f & 3) == 2)
          ckp[(size_t)((f - 2) >> 2) * NB * NCOEF + (size_t)b * NCOEF + k] = make_float2(sre, sim);
        pre = sre; pim = sim;
      }
    }
  }
}

// ---------------------------------------------------------------- fused recur + irfft + OLA
// Block (b, c): spans [4c, 4c+4). Computes frames fs..4c+3 (fs = 0 or 4c-1),
// restarting the spectral recurrence from checkpoint c-1 (state after 4c-2).
__global__ __launch_bounds__(256) void fused_resyn(const float* __restrict__ tft,
                                                   const float2* __restrict__ cur,
                                                   const float2* __restrict__ ckp,
                                                   const float* __restrict__ winT,
                                                   const float2* __restrict__ twG,
                                                   float* __restrict__ out) {
  __shared__ float L0r[1024], L0i[1024], L1r[1024], L1i[1024];
  __shared__ float2 twL[256];

  int bidx = blockIdx.x;
  int b = bidx >> 5, c = bidx & 31;
  int tid = threadIdx.x;

  twL[tid] = twG[2 * tid];

  // recurrence slots: k = tid + 256*i (i<4); thread 0 also owns k=1024 (i=4)
  float pre[5], pim[5], cgv[5], sgv[5];
#pragma unroll
  for (int i = 0; i < 5; ++i) {
    if (i == 4) { cgv[4] = -1.0f; sgv[4] = 0.0f; }
    else {
      float2 tv = twG[tid + 256 * i];
      cgv[i] = tv.x; sgv[i] = -tv.y;       // cos/sin(pi*k/1024)
    }
    pre[i] = 0.0f; pim[i] = 0.0f;
  }
  if (c > 0) {
    const float2* ck = ckp + ((size_t)(c - 1) * NB + b) * NCOEF;
#pragma unroll
    for (int i = 0; i < 5; ++i) {
      if (i == 4 && tid != 0) continue;
      int k = (i == 4) ? 1024 : tid + 256 * i;
      float2 v = ck[k];
      pre[i] = v.x; pim[i] = v.y;
    }
  }

  int fs = (c == 0) ? 0 : 4 * c - 1;
  int fe2 = 4 * c + 3;
  float ce0 = 0.0f, co0 = 0.0f, ce1 = 0.0f, co1 = 0.0f;   // carry (2nd half)
  const float* tftb = tft + (size_t)b * NFR * NCOEF;
  const float2* curb = cur + (size_t)b * 4 * NCOEF;
  const float2* win2 = (const float2*)winT;
  const float scale = 1.0f / 1024.0f;
  __syncthreads();   // twL ready

  for (int f = fs; f <= fe2; ++f) {
    const float* tfr = tftb + (size_t)f * NCOEF;
    // ---- advance recurrence (registers); tf reads now coalesced over k
    float sreg[5], simg[5];
#pragma unroll
    for (int i = 0; i < 5; ++i) {
      if (i == 4 && tid != 0) { sreg[4] = 0.0f; simg[4] = 0.0f; continue; }
      int k = (i == 4) ? 1024 : tid + 256 * i;
      float tfv = tfr[k];
      float cr = 0.0f, ci = 0.0f;
      if (f < 4) {
        float2 cv = curb[(size_t)f * NCOEF + k];
        cr = cv.x; ci = cv.y;
      }
      float rre = fmaf(pre[i], cgv[i], pim[i] * sgv[i]);
      float rim = -fmaf(pre[i], sgv[i], pim[i] * cgv[i]);
      float sre = (cr + rre) * tfv;
      float sim = (ci + rim) * tfv;
      sreg[i] = sre; simg[i] = sim;
      pre[i] = sre; pim[i] = sim;
    }
    __syncthreads();                 // prev extract done; L1 free
    // ---- X into pong planes (L1)
#pragma unroll
    for (int i = 0; i < 4; ++i) {
      int pk = PHYS(tid + 256 * i);
      L1r[pk] = sreg[i]; L1i[pk] = simg[i];
    }
    __syncthreads();
    // ---- pack Z (conj) into ping planes (L0)
#pragma unroll
    for (int it = 0; it < 4; ++it) {
      int j = tid + it * 256;
      float2 tg = twG[j];
      float cc = tg.x, sn = -tg.y;
      int pj = PHYS(j);
      float xjr = L1r[pj], xji = L1i[pj];
      float xmr, xmi;
      if (j == 0) { xmr = sreg[4]; xmi = 0.0f; }    // Nyquist (tid 0 only)
      else { int pm = PHYS(1024 - j); xmr = L1r[pm]; xmi = L1i[pm]; }
      float Xer = 0.5f * (xjr + xmr), Xei = 0.5f * (xji - xmi);
      float Xpr = 0.5f * (xjr - xmr), Xpi = 0.5f * (xji + xmi);
      float Xor_ = Xpr * cc - Xpi * sn;
      float Xoi_ = Xpr * sn + Xpi * cc;
      L0r[pj] = Xer - Xoi_;
      L0i[pj] = -(Xei + Xor_);
    }
    // ---- radix-4 Stockham, 5 stages; even st: L0->L1, odd: L1->L0
    int t = tid;
#pragma unroll
    for (int st = 0; st < 5; ++st) {
      __syncthreads();
      int s = 1 << (2 * st);
      int q = t & (s - 1);
      int j = t & ~(s - 1);
      float2 w1 = twL[j];
      float w1x = w1.x, w1y = w1.y;
      float w2x = w1x * w1x - w1y * w1y, w2y = 2.0f * w1x * w1y;
      float w3x = w2x * w1x - w2y * w1y, w3y = w2x * w1y + w2y * w1x;
      int i0 = PHYS(t), i1 = PHYS(t + 256), i2 = PHYS(t + 512), i3 = PHYS(t + 768);
      int wb = (j << 2) + q;
      int o0 = PHYS(wb), o1 = PHYS(wb + s), o2 = PHYS(wb + 2 * s), o3 = PHYS(wb + 3 * s);
      const float *xr, *xi;
      float *yr, *yi;
      if (st & 1) { xr = L1r; xi = L1i; yr = L0r; yi = L0i; }
      else        { xr = L0r; xi = L0i; yr = L1r; yi = L1i; }
      float ar_ = xr[i0], ai_ = xi[i0];
      float br_ = xr[i1], bi_ = xi[i1];
      float cr_ = xr[i2], ci_ = xi[i2];
      float dr_ = xr[i3], di_ = xi[i3];
      float apcr = ar_ + cr_, apci = ai_ + ci_;
      float amcr = ar_ - cr_, amci = ai_ - ci_;
      float bpdr = br_ + dr_, bpdi = bi_ + di_;
      float bmdr = br_ - dr_, bmdi = bi_ - di_;
      yr[o0] = apcr + bpdr;             yi[o0] = apci + bpdi;
      float t1r = amcr + bmdi, t1i = amci - bmdr;
      yr[o1] = t1r * w1x - t1i * w1y;   yi[o1] = t1r * w1y + t1i * w1x;
      float t2r = apcr - bpdr, t2i = apci - bpdi;
      yr[o2] = t2r * w2x - t2i * w2y;   yi[o2] = t2r * w2y + t2i * w2x;
      float t3r = amcr - bmdi, t3i = amci + bmdr;
      yr[o3] = t3r * w3x - t3i * w3y;   yi[o3] = t3r * w3y + t3i * w3x;
    }
    __syncthreads();
    // result in L1 (stage 4 even). x[2m]=Re z[m]/1024, x[2m+1]=-Im z[m]/1024.
    // ---- extract: span f = first half + carried second half of f-1
#pragma unroll
    for (int it = 0; it < 2; ++it) {
      int mI = tid + it * 256;
      float2 wa = win2[mI];
      float2 wb2 = win2[mI + 512];
      int pa = PHYS(mI), pb = PHYS(mI + 512);
      float fe_ = L1r[pa] * scale * wa.x;
      float fo_ = -L1i[pa] * scale * wa.y;
      float se_ = L1r[pb] * scale * wb2.x;
      float so_ = -L1i[pb] * scale * wb2.y;
      if (f >= 4 * c) {
        float2* ob = (float2*)(out + (size_t)b * NSAMP + (size_t)f * 1024);
        float pce = it ? ce1 : ce0, pco = it ? co1 : co0;
        ob[mI] = make_float2(fe_ + pce, fo_ + pco);
      }
      if (it) { ce1 = se_; co1 = so_; } else { ce0 = se_; co0 = so_; }
    }
  }
}

// ---------------------------------------------------------------- launch
extern "C" void kernel_launch(void* const* d_in, const int* in_sizes, int n_in,
                              void* d_out, int out_size, void* d_ws, size_t ws_size,
                              hipStream_t stream) {
  const float* z    = (const float*)d_in[0];
  const float* imp  = (const float*)d_in[1];
  const float* W    = (const float*)d_in[2];
  const float* bias = (const float*)d_in[3];

  float* ws = (float*)d_ws;
  float*  tf   = ws + TF_OFF;
  float*  tft  = ws + TFT_OFF;
  float2* cur  = (float2*)(ws + CUR_OFF);
  float2* ckp  = (float2*)(ws + CK_OFF);
  float*  winT = ws + WINT_OFF;
  float2* twG  = (float2*)(ws + TW_OFF);
  float*  out  = (float*)d_out;

  init_tables<<<8, 256, 0, stream>>>(winT, twG);
  tf_gemm_mfma<<<COLS / 128, 256, 0, stream>>>(z, W, bias, tf);
  fwd_fft_kernel<<<NB * 4, 256, 0, stream>>>(imp, winT, twG, cur);
  recur_ck_t<<<(NB * NCOEF + 255) / 256, 256, 0, stream>>>(tf, cur, ckp, tft);
  fused_resyn<<<NB * NCHUNK, 256, 0, stream>>>(tft, cur, ckp, winT, twG, out);
}

// Round 7
// 102.372 us; speedup vs baseline: 2.3163x; 1.0208x over previous
//
#include <hip/hip_runtime.h>

#define NB 64
#define ZDIM 128
#define NCOEF 1025
#define NFR 128
#define COLS 131200          /* NCOEF*NFR */
#define WINSZ 2048
#define HALFW 1024
#define NSAMP 131072
#define IMPN 4096
#define NCHUNK 16            /* chunks of 8 spans */
#define NCK 15               /* checkpoints after frames 6,14,...,118 */

// workspace layout in floats
#define TF_OFF   0
#define TF_SZ    (NB*COLS)
#define TFT_OFF  (TF_OFF + TF_SZ)
#define TFT_SZ   (NB*NFR*NCOEF)
#define CUR_OFF  (TFT_OFF + TFT_SZ)
#define CUR_SZ   (NB*4*NCOEF*2)
#define CK_OFF   (CUR_OFF + CUR_SZ)
#define CK_SZ    (NCK*NB*NCOEF*2)
#define WINT_OFF (CK_OFF + CK_SZ)
#define WINT_SZ  (WINSZ)
#define TW_OFF   (WINT_OFF + WINT_SZ)
#define TW_SZ    (HALFW*2)

#define PHYS(i) ((i) ^ (((i) >> 5) & 3))

typedef short bf16x8 __attribute__((ext_vector_type(8)));
typedef float f32x4 __attribute__((ext_vector_type(4)));

// ---------------------------------------------------------------- init tables
__global__ __launch_bounds__(256) void init_tables(float* __restrict__ winT,
                                                   float2* __restrict__ twG) {
  int i = blockIdx.x * 256 + threadIdx.x;
  if (i < WINSZ) {
    winT[i] = 0.5f - 0.5f * cosf((float)(2.0 * 3.14159265358979323846 / 2048.0) * (float)i);
  }
  if (i < HALFW) {
    float ang = (float)(-2.0 * 3.14159265358979323846 / 2048.0) * (float)i;
    float sv, cv;
    sincosf(ang, &sv, &cv);
    twG[i] = make_float2(cv, sv);
  }
}

// ---------------------------------------------------------------- MFMA GEMM + squash
__device__ __forceinline__ short f2bf(float f) {
  unsigned u = __builtin_bit_cast(unsigned, f);
  u += 0x7FFFu + ((u >> 16) & 1u);      // RNE
  return (short)(u >> 16);
}

__global__ __launch_bounds__(256) void tf_gemm_mfma(const float* __restrict__ z,
                                                    const float* __restrict__ W,
                                                    const float* __restrict__ bias,
                                                    float* __restrict__ tf) {
  int tid = threadIdx.x;
  int wave = tid >> 6, lane = tid & 63;
  int colw = blockIdx.x * 128 + wave * 32;
  int lr = lane & 15;
  int lk = (lane >> 4) * 8;
  int lq = (lane >> 4) * 4;

  float bv[2];
#pragma unroll
  for (int n = 0; n < 2; ++n) bv[n] = bias[colw + 16 * n + lr];

  f32x4 acc[4][2];
#pragma unroll
  for (int m = 0; m < 4; ++m)
#pragma unroll
    for (int n = 0; n < 2; ++n)
      acc[m][n] = f32x4{bv[n], bv[n], bv[n], bv[n]};

#pragma unroll
  for (int s = 0; s < 4; ++s) {
    int k0 = s * 32 + lk;
    bf16x8 afr[4];
#pragma unroll
    for (int m = 0; m < 4; ++m) {
      const float* zp = z + (size_t)(16 * m + lr) * ZDIM + k0;
      float4 z0 = *reinterpret_cast<const float4*>(zp);
      float4 z1 = *reinterpret_cast<const float4*>(zp + 4);
      afr[m] = bf16x8{f2bf(z0.x), f2bf(z0.y), f2bf(z0.z), f2bf(z0.w),
                      f2bf(z1.x), f2bf(z1.y), f2bf(z1.z), f2bf(z1.w)};
    }
    bf16x8 bfr[2];
#pragma unroll
    for (int n = 0; n < 2; ++n) {
      const float* wp = W + (size_t)k0 * COLS + colw + 16 * n + lr;
      bfr[n] = bf16x8{f2bf(wp[0 * (size_t)COLS]), f2bf(wp[1 * (size_t)COLS]),
                      f2bf(wp[2 * (size_t)COLS]), f2bf(wp[3 * (size_t)COLS]),
                      f2bf(wp[4 * (size_t)COLS]), f2bf(wp[5 * (size_t)COLS]),
                      f2bf(wp[6 * (size_t)COLS]), f2bf(wp[7 * (size_t)COLS])};
    }
#pragma unroll
    for (int m = 0; m < 4; ++m)
#pragma unroll
      for (int n = 0; n < 2; ++n)
        acc[m][n] = __builtin_amdgcn_mfma_f32_16x16x32_bf16(afr[m], bfr[n], acc[m][n], 0, 0, 0);
  }

  const float RESR = (1.0f - 0.02f) * 0.99f;
#pragma unroll
  for (int n = 0; n < 2; ++n) {
    int col = colw + 16 * n + lr;
#pragma unroll
    for (int m = 0; m < 4; ++m) {
      int rowb = 16 * m + lq;
#pragma unroll
      for (int r = 0; r < 4; ++r) {
        float x = acc[m][n][r];
        float sg = 1.0f / (1.0f + __expf(-x));
        tf[(size_t)(rowb + r) * COLS + col] = 0.02f + sg * RESR;
      }
    }
  }
}

// ---------------------------------------------------------------- fwd 2048 FFT (radix-2)
static __device__ __forceinline__ void wg_fft2048(float* ar, float* ai,
                                                  float* br, float* bi,
                                                  const float2* tw,
                                                  float** outr, float** outi) {
  float *xr = ar, *xi = ai, *yr = br, *yi = bi;
  int m = 1;
  for (int s = 0; s < 11; ++s) {
    __syncthreads();
#pragma unroll
    for (int it = 0; it < 4; ++it) {
      int t = (int)threadIdx.x + it * 256;
      int jm = t & ~(m - 1);
      float x0r = xr[t], x0i = xi[t];
      float x1r = xr[t + 1024], x1i = xi[t + 1024];
      float2 w = tw[jm];
      float sr = x0r + x1r, si = x0i + x1i;
      float dr = x0r - x1r, di = x0i - x1i;
      float pr = dr * w.x - di * w.y;
      float pi = dr * w.y + di * w.x;
      yr[t + jm] = sr;      yi[t + jm] = si;
      yr[t + jm + m] = pr;  yi[t + jm + m] = pi;
    }
    float* t0 = xr; xr = yr; yr = t0;
    float* t1 = xi; xi = yi; yi = t1;
    m <<= 1;
  }
  __syncthreads();
  *outr = xr; *outi = xi;
}

__global__ __launch_bounds__(256) void fwd_fft_kernel(const float* __restrict__ imp,
                                                      const float* __restrict__ winT,
                                                      const float2* __restrict__ twG,
                                                      float2* __restrict__ cur) {
  __shared__ float b0r[WINSZ], b0i[WINSZ], b1r[WINSZ], b1i[WINSZ];
  __shared__ float2 tw[HALFW];
  int wg = blockIdx.x;
  int b = wg >> 2, f = wg & 3;
  int tid = threadIdx.x;

  for (int i = tid; i < HALFW; i += 256) tw[i] = twG[i];
  for (int w = tid; w < WINSZ; w += 256) {
    int s = f * HALFW + w;
    float v = (s < IMPN) ? imp[(size_t)b * IMPN + s] * winT[w] : 0.0f;
    b0r[w] = v;
    b0i[w] = 0.0f;
  }
  float *rr, *ri;
  wg_fft2048(b0r, b0i, b1r, b1i, tw, &rr, &ri);
  for (int k = tid; k < NCOEF; k += 256)
    cur[(size_t)wg * NCOEF + k] = make_float2(rr[k], ri[k]);
}

// ---------------------------------------------------------------- recurrence checkpoints + tf transpose
__global__ __launch_bounds__(256) void recur_ck_t(const float* __restrict__ tf,
                                                  const float2* __restrict__ cur,
                                                  float2* __restrict__ ckp,
                                                  float* __restrict__ tft) {
  int id = blockIdx.x * 256 + threadIdx.x;
  if (id >= NB * NCOEF) return;
  int b = id / NCOEF;
  int k = id - b * NCOEF;

  float g = 3.14159265358979323846f * (float)k / 1024.0f;
  float sg, cg;
  sincosf(g, &sg, &cg);
  bool herm = (k == 0) || (k == HALFW);

  const float4* tf4 = (const float4*)(tf + (size_t)b * COLS + (size_t)k * NFR);
  const float2* curb = cur + (size_t)b * 4 * NCOEF + k;
  float* tftb = tft + (size_t)b * NFR * NCOEF + k;

  float pre = 0.0f, pim = 0.0f;
  for (int f4 = 0; f4 < 32; ++f4) {
    float4 tv = tf4[f4];
    float tfs[4] = {tv.x, tv.y, tv.z, tv.w};
#pragma unroll
    for (int u = 0; u < 4; ++u) {
      int f = 4 * f4 + u;
      tftb[(size_t)f * NCOEF] = tfs[u];       // coalesced transpose write
      if (f < 120) {                           // recurrence needed thru f=118
        float tfv = tfs[u];
        float cr = 0.0f, ci = 0.0f;
        if (f < 4) {
          float2 cv = curb[(size_t)f * NCOEF];
          cr = cv.x; ci = cv.y;
        }
        float ire = herm ? 0.0f : pim;
        float rre = fmaf(pre, cg, ire * sg);
        float rim = -fmaf(pre, sg, ire * cg);
        float sre = (cr + rre) * tfv;
        float sim = (ci + rim) * tfv;
        if ((f & 7) == 6)
          ckp[(size_t)((f - 6) >> 3) * NB * NCOEF + (size_t)b * NCOEF + k] = make_float2(sre, sim);
        pre = sre; pim = sim;
      }
    }
  }
}

// ---------------------------------------------------------------- fused recur + dual irfft + OLA
// Block (b,c): 8 spans [8c,8c+8), frames fs..8c+7 (fs = 0 or 8c-1) from
// checkpoint c-1 (state after 8c-2). Frames processed in PAIRS: advance
// recurrence 2 frames in registers, then 2 independent interleaved radix-4
// 1024-pt IFFTs in float2 LDS planes. No atomics; output written once.
__global__ __launch_bounds__(256) void fused_resyn(const float* __restrict__ tft,
                                                   const float2* __restrict__ cur,
                                                   const float2* __restrict__ ckp,
                                                   const float* __restrict__ winT,
                                                   const float2* __restrict__ twG,
                                                   float* __restrict__ out) {
  __shared__ float2 PA0[1024], PB0[1024];   // ping (A,B)
  __shared__ float2 PA1[1024], PB1[1024];   // pong (A,B)
  __shared__ float2 twL[256];
  __shared__ float nyqv[2];

  int bidx = blockIdx.x;
  int b = bidx >> 4, c = bidx & 15;
  int tid = threadIdx.x;
  twL[tid] = twG[2 * tid];

  // recurrence slots: k = tid + 256*i (i<4); thread 0 also owns k=1024 (i=4)
  float pre[5], pim[5], cgv[5], sgv[5];
#pragma unroll
  for (int i = 0; i < 5; ++i) {
    if (i == 4) { cgv[4] = -1.0f; sgv[4] = 0.0f; }
    else {
      float2 tv = twG[tid + 256 * i];
      cgv[i] = tv.x; sgv[i] = -tv.y;       // cos/sin(pi*k/1024)
    }
    pre[i] = 0.0f; pim[i] = 0.0f;
  }
  if (c > 0) {
    const float2* ck = ckp + ((size_t)(c - 1) * NB + b) * NCOEF;
#pragma unroll
    for (int i = 0; i < 5; ++i) {
      if (i == 4 && tid != 0) continue;
      int k = (i == 4) ? 1024 : tid + 256 * i;
      float2 v = ck[k];
      pre[i] = v.x; pim[i] = v.y;
    }
  }

  const float* tftb = tft + (size_t)b * NFR * NCOEF;
  const float2* curb = cur + (size_t)b * 4 * NCOEF;
  const float2* win2 = (const float2*)winT;
  int fs = (c == 0) ? 0 : 8 * c - 1;
  int fe = 8 * c + 7;
  float ce[2] = {0.0f, 0.0f}, co[2] = {0.0f, 0.0f};   // carry (2nd half of prev frame)

#define ADVANCE(F, S, I)                                                     \
  do {                                                                       \
    const float* tfr_ = tftb + (size_t)(F) * NCOEF;                          \
    _Pragma("unroll")                                                        \
    for (int i_ = 0; i_ < 5; ++i_) {                                         \
      if (i_ == 4 && tid != 0) { S[4] = 0.0f; I[4] = 0.0f; continue; }       \
      int k_ = (i_ == 4) ? 1024 : tid + 256 * i_;                            \
      float tfv_ = tfr_[k_];                                                 \
      float cr_ = 0.0f, ci_ = 0.0f;                                          \
      if ((F) < 4) {                                                         \
        float2 cv_ = curb[(size_t)(F) * NCOEF + k_];                         \
        cr_ = cv_.x; ci_ = cv_.y;                                            \
      }                                                                      \
      float rre_ = fmaf(pre[i_], cgv[i_], pim[i_] * sgv[i_]);                \
      float rim_ = -fmaf(pre[i_], sgv[i_], pim[i_] * cgv[i_]);               \
      S[i_] = (cr_ + rre_) * tfv_;                                           \
      I[i_] = (ci_ + rim_) * tfv_;                                           \
      pre[i_] = S[i_]; pim[i_] = I[i_];                                      \
    }                                                                        \
  } while (0)

  __syncthreads();   // twL ready

  for (int fA = fs; fA <= fe; fA += 2) {
    int fB = fA + 1;
    bool hasB = (fB <= fe);

    float sA[5], iA[5], sB[5], iB[5];
    ADVANCE(fA, sA, iA);
    if (hasB) ADVANCE(fB, sB, iB);
    else {
#pragma unroll
      for (int i = 0; i < 5; ++i) { sB[i] = 0.0f; iB[i] = 0.0f; }
    }

    __syncthreads();                 // prev extract done; pong planes free
    // ---- X into pong planes
#pragma unroll
    for (int i = 0; i < 4; ++i) {
      int pk = PHYS(tid + 256 * i);
      PA1[pk] = make_float2(sA[i], iA[i]);
      PB1[pk] = make_float2(sB[i], iB[i]);
    }
    if (tid == 0) { nyqv[0] = sA[4]; nyqv[1] = sB[4]; }
    __syncthreads();

    // ---- pack Z (conj, scale folded) into ping planes
    const float Cs = 0.5f / 1024.0f;
#pragma unroll
    for (int it = 0; it < 4; ++it) {
      int j = tid + it * 256;
      float2 tg = twG[j];
      float cc = tg.x, sn = -tg.y;
      int pj = PHYS(j);
      int pm = PHYS((HALFW - j) & 1023);
      {
        float2 xj = PA1[pj];
        float xmr, xmi;
        if (j == 0) { xmr = nyqv[0]; xmi = 0.0f; }
        else { float2 xm = PA1[pm]; xmr = xm.x; xmi = xm.y; }
        float Xer = Cs * (xj.x + xmr), Xei = Cs * (xj.y - xmi);
        float Xpr = Cs * (xj.x - xmr), Xpi = Cs * (xj.y + xmi);
        float Xor_ = Xpr * cc - Xpi * sn;
        float Xoi_ = Xpr * sn + Xpi * cc;
        PA0[pj] = make_float2(Xer - Xoi_, -(Xei + Xor_));
      }
      {
        float2 xj = PB1[pj];
        float xmr, xmi;
        if (j == 0) { xmr = nyqv[1]; xmi = 0.0f; }
        else { float2 xm = PB1[pm]; xmr = xm.x; xmi = xm.y; }
        float Xer = Cs * (xj.x + xmr), Xei = Cs * (xj.y - xmi);
        float Xpr = Cs * (xj.x - xmr), Xpi = Cs * (xj.y + xmi);
        float Xor_ = Xpr * cc - Xpi * sn;
        float Xoi_ = Xpr * sn + Xpi * cc;
        PB0[pj] = make_float2(Xer - Xoi_, -(Xei + Xor_));
      }
    }

    // ---- dual radix-4 Stockham, 5 stages (even st: ping->pong)
    int i0 = PHYS(tid), i1 = PHYS(tid + 256), i2 = PHYS(tid + 512), i3 = PHYS(tid + 768);
#pragma unroll
    for (int st = 0; st < 5; ++st) {
      __syncthreads();
      int s = 1 << (2 * st);
      int q = tid & (s - 1);
      int j = tid & ~(s - 1);
      float2 w1 = twL[j];
      float w1x = w1.x, w1y = w1.y;
      float w2x = w1x * w1x - w1y * w1y, w2y = 2.0f * w1x * w1y;
      float w3x = w2x * w1x - w2y * w1y, w3y = w2x * w1y + w2y * w1x;
      int wb = (j << 2) + q;
      int o0 = PHYS(wb), o1 = PHYS(wb + s), o2 = PHYS(wb + 2 * s), o3 = PHYS(wb + 3 * s);
      const float2 *xA, *xB;
      float2 *yA, *yB;
      if (st & 1) { xA = PA1; xB = PB1; yA = PA0; yB = PB0; }
      else        { xA = PA0; xB = PB0; yA = PA1; yB = PB1; }

#define BFLY4(X, Y)                                                          \
      do {                                                                   \
        float2 a_ = X[i0], b_ = X[i1], c_ = X[i2], d_ = X[i3];               \
        float apcr = a_.x + c_.x, apci = a_.y + c_.y;                        \
        float amcr = a_.x - c_.x, amci = a_.y - c_.y;                        \
        float bpdr = b_.x + d_.x, bpdi = b_.y + d_.y;                        \
        float bmdr = b_.x - d_.x, bmdi = b_.y - d_.y;                        \
        Y[o0] = make_float2(apcr + bpdr, apci + bpdi);                       \
        float t1r = amcr + bmdi, t1i = amci - bmdr;                          \
        Y[o1] = make_float2(t1r * w1x - t1i * w1y, t1r * w1y + t1i * w1x);   \
        float t2r = apcr - bpdr, t2i = apci - bpdi;                          \
        Y[o2] = make_float2(t2r * w2x - t2i * w2y, t2r * w2y + t2i * w2x);   \
        float t3r = amcr - bmdi, t3i = amci + bmdr;                          \
        Y[o3] = make_float2(t3r * w3x - t3i * w3y, t3r * w3y + t3i * w3x);   \
      } while (0)

      BFLY4(xA, yA);
      BFLY4(xB, yB);
#undef BFLY4
    }
    __syncthreads();
    // final in pong. x[2m]=Re, x[2m+1]=-Im (scale already folded).

    // ---- extract spans fA, fB with register carry
#pragma unroll
    for (int it = 0; it < 2; ++it) {
      int mI = tid + it * 256;
      int pa = PHYS(mI), pb = PHYS(mI + 512);
      float2 wva = win2[mI], wvb = win2[mI + 512];
      float2 a1 = PA1[pa], a2 = PA1[pb];
      float fe_ = a1.x * wva.x, fo_ = -a1.y * wva.y;
      if (fA >= 8 * c) {
        float2* ob = (float2*)(out + (size_t)b * NSAMP + (size_t)fA * 1024);
        ob[mI] = make_float2(fe_ + ce[it], fo_ + co[it]);
      }
      float nce = a2.x * wvb.x, nco = -a2.y * wvb.y;
      if (hasB) {
        float2 b1 = PB1[pa], b2 = PB1[pb];
        float2* ob = (float2*)(out + (size_t)b * NSAMP + (size_t)fB * 1024);
        ob[mI] = make_float2(b1.x * wva.x + nce, -b1.y * wva.y + nco);
        nce = b2.x * wvb.x; nco = -b2.y * wvb.y;
      }
      ce[it] = nce; co[it] = nco;
    }
  }
#undef ADVANCE
}

// ---------------------------------------------------------------- launch
extern "C" void kernel_launch(void* const* d_in, const int* in_sizes, int n_in,
                              void* d_out, int out_size, void* d_ws, size_t ws_size,
                              hipStream_t stream) {
  const float* z    = (const float*)d_in[0];
  const float* imp  = (const float*)d_in[1];
  const float* W    = (const float*)d_in[2];
  const float* bias = (const float*)d_in[3];

  float* ws = (float*)d_ws;
  float*  tf   = ws + TF_OFF;
  float*  tft  = ws + TFT_OFF;
  float2* cur  = (float2*)(ws + CUR_OFF);
  float2* ckp  = (float2*)(ws + CK_OFF);
  float*  winT = ws + WINT_OFF;
  float2* twG  = (float2*)(ws + TW_OFF);
  float*  out  = (float*)d_out;

  init_tables<<<8, 256, 0, stream>>>(winT, twG);
  tf_gemm_mfma<<<COLS / 128, 256, 0, stream>>>(z, W, bias, tf);
  fwd_fft_kernel<<<NB * 4, 256, 0, stream>>>(imp, winT, twG, cur);
  recur_ck_t<<<(NB * NCOEF + 255) / 256, 256, 0, stream>>>(tf, cur, ckp, tft);
  fused_resyn<<<NB * NCHUNK, 256, 0, stream>>>(tft, cur, ckp, winT, twG, out);
}

// Round 8
// 96.265 us; speedup vs baseline: 2.4632x; 1.0634x over previous
//
#include <hip/hip_runtime.h>

#define NB 64
#define ZDIM 128
#define NCOEF 1025
#define NFR 128
#define COLS 131200          /* NCOEF*NFR */
#define WINSZ 2048
#define HALFW 1024
#define NSAMP 131072
#define IMPN 4096
#define NCHUNK 32            /* chunks of 4 spans */
#define NCK 31               /* checkpoints after frames 2,6,...,122 */

// workspace layout in floats
#define TF_OFF   0
#define TF_SZ    (NB*COLS)
#define TFT_OFF  (TF_OFF + TF_SZ)
#define TFT_SZ   (NB*NFR*NCOEF)
#define CUR_OFF  (TFT_OFF + TFT_SZ)
#define CUR_SZ   (NB*4*NCOEF*2)
#define CK_OFF   (CUR_OFF + CUR_SZ)
#define CK_SZ    (NCK*NB*NCOEF*2)
#define WINT_OFF (CK_OFF + CK_SZ)
#define WINT_SZ  (WINSZ)
#define TW_OFF   (WINT_OFF + WINT_SZ)
#define TW_SZ    (HALFW*2)

// 2-bit XOR swizzle for the FFT plane: bits[3:2] ^= bits[5:4]
#define PHI(p) ((p) ^ ((((p) >> 4) & 3) << 2))

typedef short bf16x8 __attribute__((ext_vector_type(8)));
typedef float f32x4 __attribute__((ext_vector_type(4)));

__device__ __forceinline__ float2 cmul(float2 a, float2 b) {
  return make_float2(a.x * b.x - a.y * b.y, a.x * b.y + a.y * b.x);
}

// ---------------------------------------------------------------- init tables
__global__ __launch_bounds__(256) void init_tables(float* __restrict__ winT,
                                                   float2* __restrict__ twG) {
  int i = blockIdx.x * 256 + threadIdx.x;
  if (i < WINSZ) {
    winT[i] = 0.5f - 0.5f * cosf((float)(2.0 * 3.14159265358979323846 / 2048.0) * (float)i);
  }
  if (i < HALFW) {
    float ang = (float)(-2.0 * 3.14159265358979323846 / 2048.0) * (float)i;
    float sv, cv;
    sincosf(ang, &sv, &cv);
    twG[i] = make_float2(cv, sv);
  }
}

// ---------------------------------------------------------------- MFMA GEMM + squash
__device__ __forceinline__ short f2bf(float f) {
  unsigned u = __builtin_bit_cast(unsigned, f);
  u += 0x7FFFu + ((u >> 16) & 1u);      // RNE
  return (short)(u >> 16);
}

__global__ __launch_bounds__(256) void tf_gemm_mfma(const float* __restrict__ z,
                                                    const float* __restrict__ W,
                                                    const float* __restrict__ bias,
                                                    float* __restrict__ tf) {
  int tid = threadIdx.x;
  int wave = tid >> 6, lane = tid & 63;
  int colw = blockIdx.x * 128 + wave * 32;
  int lr = lane & 15;
  int lk = (lane >> 4) * 8;
  int lq = (lane >> 4) * 4;

  float bv[2];
#pragma unroll
  for (int n = 0; n < 2; ++n) bv[n] = bias[colw + 16 * n + lr];

  f32x4 acc[4][2];
#pragma unroll
  for (int m = 0; m < 4; ++m)
#pragma unroll
    for (int n = 0; n < 2; ++n)
      acc[m][n] = f32x4{bv[n], bv[n], bv[n], bv[n]};

#pragma unroll
  for (int s = 0; s < 4; ++s) {
    int k0 = s * 32 + lk;
    bf16x8 afr[4];
#pragma unroll
    for (int m = 0; m < 4; ++m) {
      const float* zp = z + (size_t)(16 * m + lr) * ZDIM + k0;
      float4 z0 = *reinterpret_cast<const float4*>(zp);
      float4 z1 = *reinterpret_cast<const float4*>(zp + 4);
      afr[m] = bf16x8{f2bf(z0.x), f2bf(z0.y), f2bf(z0.z), f2bf(z0.w),
                      f2bf(z1.x), f2bf(z1.y), f2bf(z1.z), f2bf(z1.w)};
    }
    bf16x8 bfr[2];
#pragma unroll
    for (int n = 0; n < 2; ++n) {
      const float* wp = W + (size_t)k0 * COLS + colw + 16 * n + lr;
      bfr[n] = bf16x8{f2bf(wp[0 * (size_t)COLS]), f2bf(wp[1 * (size_t)COLS]),
                      f2bf(wp[2 * (size_t)COLS]), f2bf(wp[3 * (size_t)COLS]),
                      f2bf(wp[4 * (size_t)COLS]), f2bf(wp[5 * (size_t)COLS]),
                      f2bf(wp[6 * (size_t)COLS]), f2bf(wp[7 * (size_t)COLS])};
    }
#pragma unroll
    for (int m = 0; m < 4; ++m)
#pragma unroll
      for (int n = 0; n < 2; ++n)
        acc[m][n] = __builtin_amdgcn_mfma_f32_16x16x32_bf16(afr[m], bfr[n], acc[m][n], 0, 0, 0);
  }

  const float RESR = (1.0f - 0.02f) * 0.99f;
#pragma unroll
  for (int n = 0; n < 2; ++n) {
    int col = colw + 16 * n + lr;
#pragma unroll
    for (int m = 0; m < 4; ++m) {
      int rowb = 16 * m + lq;
#pragma unroll
      for (int r = 0; r < 4; ++r) {
        float x = acc[m][n][r];
        float sg = 1.0f / (1.0f + __expf(-x));
        tf[(size_t)(rowb + r) * COLS + col] = 0.02f + sg * RESR;
      }
    }
  }
}

// ---------------------------------------------------------------- fwd 2048 FFT (radix-2)
static __device__ __forceinline__ void wg_fft2048(float* ar, float* ai,
                                                  float* br, float* bi,
                                                  const float2* tw,
                                                  float** outr, float** outi) {
  float *xr = ar, *xi = ai, *yr = br, *yi = bi;
  int m = 1;
  for (int s = 0; s < 11; ++s) {
    __syncthreads();
#pragma unroll
    for (int it = 0; it < 4; ++it) {
      int t = (int)threadIdx.x + it * 256;
      int jm = t & ~(m - 1);
      float x0r = xr[t], x0i = xi[t];
      float x1r = xr[t + 1024], x1i = xi[t + 1024];
      float2 w = tw[jm];
      float sr = x0r + x1r, si = x0i + x1i;
      float dr = x0r - x1r, di = x0i - x1i;
      float pr = dr * w.x - di * w.y;
      float pi = dr * w.y + di * w.x;
      yr[t + jm] = sr;      yi[t + jm] = si;
      yr[t + jm + m] = pr;  yi[t + jm + m] = pi;
    }
    float* t0 = xr; xr = yr; yr = t0;
    float* t1 = xi; xi = yi; yi = t1;
    m <<= 1;
  }
  __syncthreads();
  *outr = xr; *outi = xi;
}

__global__ __launch_bounds__(256) void fwd_fft_kernel(const float* __restrict__ imp,
                                                      const float* __restrict__ winT,
                                                      const float2* __restrict__ twG,
                                                      float2* __restrict__ cur) {
  __shared__ float b0r[WINSZ], b0i[WINSZ], b1r[WINSZ], b1i[WINSZ];
  __shared__ float2 tw[HALFW];
  int wg = blockIdx.x;
  int b = wg >> 2, f = wg & 3;
  int tid = threadIdx.x;

  for (int i = tid; i < HALFW; i += 256) tw[i] = twG[i];
  for (int w = tid; w < WINSZ; w += 256) {
    int s = f * HALFW + w;
    float v = (s < IMPN) ? imp[(size_t)b * IMPN + s] * winT[w] : 0.0f;
    b0r[w] = v;
    b0i[w] = 0.0f;
  }
  float *rr, *ri;
  wg_fft2048(b0r, b0i, b1r, b1i, tw, &rr, &ri);
  for (int k = tid; k < NCOEF; k += 256)
    cur[(size_t)wg * NCOEF + k] = make_float2(rr[k], ri[k]);
}

// ---------------------------------------------------------------- recurrence checkpoints + tf transpose
// Stores state after frames 2,6,...,122 (31 ckpts) AND writes tft[b][f][k].
__global__ __launch_bounds__(256) void recur_ck_t(const float* __restrict__ tf,
                                                  const float2* __restrict__ cur,
                                                  float2* __restrict__ ckp,
                                                  float* __restrict__ tft) {
  int id = blockIdx.x * 256 + threadIdx.x;
  if (id >= NB * NCOEF) return;
  int b = id / NCOEF;
  int k = id - b * NCOEF;

  float g = 3.14159265358979323846f * (float)k / 1024.0f;
  float sg, cg;
  sincosf(g, &sg, &cg);
  bool herm = (k == 0) || (k == HALFW);

  const float4* tf4 = (const float4*)(tf + (size_t)b * COLS + (size_t)k * NFR);
  const float2* curb = cur + (size_t)b * 4 * NCOEF + k;
  float* tftb = tft + (size_t)b * NFR * NCOEF + k;

  float pre = 0.0f, pim = 0.0f;
  for (int f4 = 0; f4 < 32; ++f4) {
    float4 tv = tf4[f4];
    float tfs[4] = {tv.x, tv.y, tv.z, tv.w};
#pragma unroll
    for (int u = 0; u < 4; ++u) {
      int f = 4 * f4 + u;
      tftb[(size_t)f * NCOEF] = tfs[u];       // coalesced transpose write
      if (f < 124) {
        float tfv = tfs[u];
        float cr = 0.0f, ci = 0.0f;
        if (f < 4) {
          float2 cv = curb[(size_t)f * NCOEF];
          cr = cv.x; ci = cv.y;
        }
        float ire = herm ? 0.0f : pim;
        float rre = fmaf(pre, cg, ire * sg);
        float rim = -fmaf(pre, sg, ire * cg);
        float sre = (cr + rre) * tfv;
        float sim = (ci + rim) * tfv;
        if ((f & 3) == 2)
          ckp[(size_t)((f - 2) >> 2) * NB * NCOEF + (size_t)b * NCOEF + k] = make_float2(sre, sim);
        pre = sre; pim = sim;
      }
    }
  }
}

// ---------------------------------------------------------------- fused recur + irfft + OLA
// Register-resident DIF radix-4 1024-pt FFT. Stage 1 cross-wave (via one 8KB
// plane); stages 2-5 wave-local (barrier-free). Output digit-reversed; the
// extract folds digit-reversal into per-thread frame-invariant positions.
// 4 barriers/frame. No atomics.
__global__ __launch_bounds__(256) void fused_resyn(const float* __restrict__ tft,
                                                   const float2* __restrict__ cur,
                                                   const float2* __restrict__ ckp,
                                                   const float* __restrict__ winT,
                                                   const float2* __restrict__ twG,
                                                   float* __restrict__ out) {
  __shared__ float2 P[1024];

  int bidx = blockIdx.x;
  int b = bidx >> 5, c = bidx & 31;
  int t = threadIdx.x;

  // ---- recurrence slots: k = t + 256*i (i<4); thread 0 also owns k=1024
  float pre[5], pim[5], cgv[5], sgv[5];
#pragma unroll
  for (int i = 0; i < 5; ++i) {
    if (i == 4) { cgv[4] = -1.0f; sgv[4] = 0.0f; }
    else {
      float2 tv = twG[t + 256 * i];
      cgv[i] = tv.x; sgv[i] = -tv.y;       // cos/sin(pi*k/1024)
    }
    pre[i] = 0.0f; pim[i] = 0.0f;
  }
  if (c > 0) {
    const float2* ck = ckp + ((size_t)(c - 1) * NB + b) * NCOEF;
#pragma unroll
    for (int i = 0; i < 5; ++i) {
      if (i == 4 && t != 0) continue;
      int k = (i == 4) ? 1024 : t + 256 * i;
      float2 v = ck[k];
      pre[i] = v.x; pim[i] = v.y;
    }
  }

  // ---- twiddle preloads (W = e^{-2pi i/1024}; twG[j]=e^{-2pi i j/2048})
  float2 w1a = twG[2 * t];            float2 w1b = cmul(w1a, w1a); float2 w1c = cmul(w1b, w1a);
  float2 w2a = twG[8 * (t & 63)];     float2 w2b = cmul(w2a, w2a); float2 w2c = cmul(w2b, w2a);
  float2 w3a = twG[32 * (t & 15)];    float2 w3b = cmul(w3a, w3a); float2 w3c = cmul(w3b, w3a);
  float2 w4a = twG[128 * (t & 3)];    float2 w4b = cmul(w4a, w4a); float2 w4c = cmul(w4b, w4a);
  // pack twiddles per i (j = t + 256*i)
  float2 twp0 = twG[t], twp1 = twG[t + 256], twp2 = twG[t + 512], twp3 = twG[t + 768];

  // ---- extract constants: thread holds z[m] at m = mb + 256q (digit-reversed)
  int mb = (t >> 6) + ((t >> 4) & 3) * 4 + ((t >> 2) & 3) * 16 + (t & 3) * 64;
  const float2* win2 = (const float2*)winT;
  float2 wv0 = win2[mb], wv1 = win2[mb + 256], wv2 = win2[mb + 512], wv3 = win2[mb + 768];

  // ---- LDS address constants (swizzled)
  int X0 = PHI(t);                                   // X write: X0+256i; y write: X0q? (see below)
  int B2 = 256 * (t >> 6) + ((t & 63) ^ (((t >> 4) & 3) << 2));   // stage2 base
  int b3h = 64 * (t >> 4), i3 = t & 15;
  int b4h = 16 * (t >> 2), i4 = t & 3, c4 = (t >> 2) & 3;
  int p5 = b4h + 4 * ((t & 3) ^ c4);                 // stage5 quad base (phi'd)
  // mirror read addrs for pack (j = t+256i -> 1024-j), phi'd
  int pm0 = PHI((1024 - t) & 1023);
  int pm1 = PHI((1024 - (t + 256)) & 1023);
  int pm2 = PHI((1024 - (t + 512)) & 1023);
  int pm3 = PHI((1024 - (t + 768)) & 1023);

  const float* tftb = tft + (size_t)b * NFR * NCOEF;
  const float2* curb = cur + (size_t)b * 4 * NCOEF;
  const float Cs = 0.5f / 1024.0f;

  int fs = (c == 0) ? 0 : 4 * c - 1;
  int fe = 4 * c + 3;
  float carE0 = 0.0f, carO0 = 0.0f, carE1 = 0.0f, carO1 = 0.0f;

  for (int f = fs; f <= fe; ++f) {
    // ---- advance recurrence (registers)
    float S[5], I[5];
    {
      const float* tfr = tftb + (size_t)f * NCOEF;
#pragma unroll
      for (int i = 0; i < 5; ++i) {
        if (i == 4 && t != 0) { S[4] = 0.0f; I[4] = 0.0f; continue; }
        int k = (i == 4) ? 1024 : t + 256 * i;
        float tfv = tfr[k];
        float cr = 0.0f, ci = 0.0f;
        if (f < 4) {
          float2 cv = curb[(size_t)f * NCOEF + k];
          cr = cv.x; ci = cv.y;
        }
        float rre = fmaf(pre[i], cgv[i], pim[i] * sgv[i]);
        float rim = -fmaf(pre[i], sgv[i], pim[i] * cgv[i]);
        S[i] = (cr + rre) * tfv;
        I[i] = (ci + rim) * tfv;
        pre[i] = S[i]; pim[i] = I[i];
      }
    }

    __syncthreads();                       // (1) plane free (prev frame done)
    // ---- X into plane (natural order, swizzled)
#pragma unroll
    for (int i = 0; i < 4; ++i)
      P[X0 + 256 * i] = make_float2(S[i], I[i]);
    __syncthreads();                       // (2) X visible

    // ---- pack Z (own X from regs; mirror from plane) + stage-1 butterfly
    float2 Z[4];
    {
      float2 xm[4];
      xm[0] = (t == 0) ? make_float2(S[4], 0.0f) : P[pm0];
      xm[1] = P[pm1]; xm[2] = P[pm2]; xm[3] = P[pm3];
      float2 twp[4] = {twp0, twp1, twp2, twp3};
#pragma unroll
      for (int i = 0; i < 4; ++i) {
        float xjr = S[i], xji = I[i];
        float cc = twp[i].x, sn = -twp[i].y;   // e^{+2pi i j/2048}
        float Xer = Cs * (xjr + xm[i].x), Xei = Cs * (xji - xm[i].y);
        float Xpr = Cs * (xjr - xm[i].x), Xpi = Cs * (xji + xm[i].y);
        float Xor_ = Xpr * cc - Xpi * sn;
        float Xoi_ = Xpr * sn + Xpi * cc;
        Z[i] = make_float2(Xer - Xoi_, -(Xei + Xor_));
      }
    }
    float2 y0, y1, y2, y3;
    {
      float2 A = make_float2(Z[0].x + Z[2].x, Z[0].y + Z[2].y);
      float2 Bv = make_float2(Z[0].x - Z[2].x, Z[0].y - Z[2].y);
      float2 Cv = make_float2(Z[1].x + Z[3].x, Z[1].y + Z[3].y);
      float2 D = make_float2(Z[1].x - Z[3].x, Z[1].y - Z[3].y);
      y0 = make_float2(A.x + Cv.x, A.y + Cv.y);
      y1 = cmul(make_float2(Bv.x + D.y, Bv.y - D.x), w1a);   // (B - iD) W^t
      y2 = cmul(make_float2(A.x - Cv.x, A.y - Cv.y), w1b);
      y3 = cmul(make_float2(Bv.x - D.y, Bv.y + D.x), w1c);
    }
    __syncthreads();                       // (3) mirror reads done; plane writable
    P[X0]       = y0;                      // pos 256q + t, phi'd = X0 + 256q
    P[X0 + 256] = y1;
    P[X0 + 512] = y2;
    P[X0 + 768] = y3;
    __syncthreads();                       // (4) y visible across waves

    // ---- stage 2 (wave-local, N=256): read B2+64r, write B2+64q
    float2 u0 = P[B2], u1 = P[B2 + 64], u2 = P[B2 + 128], u3 = P[B2 + 192];
    {
      float2 A = make_float2(u0.x + u2.x, u0.y + u2.y);
      float2 Bv = make_float2(u0.x - u2.x, u0.y - u2.y);
      float2 Cv = make_float2(u1.x + u3.x, u1.y + u3.y);
      float2 D = make_float2(u1.x - u3.x, u1.y - u3.y);
      P[B2]       = make_float2(A.x + Cv.x, A.y + Cv.y);
      P[B2 + 64]  = cmul(make_float2(Bv.x + D.y, Bv.y - D.x), w2a);
      P[B2 + 128] = cmul(make_float2(A.x - Cv.x, A.y - Cv.y), w2b);
      P[B2 + 192] = cmul(make_float2(Bv.x - D.y, Bv.y + D.x), w2c);
    }
    asm volatile("s_waitcnt lgkmcnt(0)" ::: "memory");

    // ---- stage 3 (N=64): addr_r = 64(t>>4) + 16r + (i3 ^ (r<<2))
    u0 = P[b3h + i3];
    u1 = P[b3h + 16 + (i3 ^ 4)];
    u2 = P[b3h + 32 + (i3 ^ 8)];
    u3 = P[b3h + 48 + (i3 ^ 12)];
    {
      float2 A = make_float2(u0.x + u2.x, u0.y + u2.y);
      float2 Bv = make_float2(u0.x - u2.x, u0.y - u2.y);
      float2 Cv = make_float2(u1.x + u3.x, u1.y + u3.y);
      float2 D = make_float2(u1.x - u3.x, u1.y - u3.y);
      P[b3h + i3]             = make_float2(A.x + Cv.x, A.y + Cv.y);
      P[b3h + 16 + (i3 ^ 4)]  = cmul(make_float2(Bv.x + D.y, Bv.y - D.x), w3a);
      P[b3h + 32 + (i3 ^ 8)]  = cmul(make_float2(A.x - Cv.x, A.y - Cv.y), w3b);
      P[b3h + 48 + (i3 ^ 12)] = cmul(make_float2(Bv.x - D.y, Bv.y + D.x), w3c);
    }
    asm volatile("s_waitcnt lgkmcnt(0)" ::: "memory");

    // ---- stage 4 (N=16): addr_r = 16(t>>2) + 4*(r^c4) + i4
    u0 = P[b4h + 4 * (0 ^ c4) + i4];
    u1 = P[b4h + 4 * (1 ^ c4) + i4];
    u2 = P[b4h + 4 * (2 ^ c4) + i4];
    u3 = P[b4h + 4 * (3 ^ c4) + i4];
    {
      float2 A = make_float2(u0.x + u2.x, u0.y + u2.y);
      float2 Bv = make_float2(u0.x - u2.x, u0.y - u2.y);
      float2 Cv = make_float2(u1.x + u3.x, u1.y + u3.y);
      float2 D = make_float2(u1.x - u3.x, u1.y - u3.y);
      P[b4h + 4 * (0 ^ c4) + i4] = make_float2(A.x + Cv.x, A.y + Cv.y);
      P[b4h + 4 * (1 ^ c4) + i4] = cmul(make_float2(Bv.x + D.y, Bv.y - D.x), w4a);
      P[b4h + 4 * (2 ^ c4) + i4] = cmul(make_float2(A.x - Cv.x, A.y - Cv.y), w4b);
      P[b4h + 4 * (3 ^ c4) + i4] = cmul(make_float2(Bv.x - D.y, Bv.y + D.x), w4c);
    }
    asm volatile("s_waitcnt lgkmcnt(0)" ::: "memory");

    // ---- stage 5 (N=4, quad in consecutive addrs, no twiddles) -> regs
    float4 q01 = *reinterpret_cast<const float4*>(&P[p5]);
    float4 q23 = *reinterpret_cast<const float4*>(&P[p5 + 2]);
    float2 z0, z1, z2, z3;
    {
      float2 a = make_float2(q01.x, q01.y), bq = make_float2(q01.z, q01.w);
      float2 cq = make_float2(q23.x, q23.y), d = make_float2(q23.z, q23.w);
      float2 A = make_float2(a.x + cq.x, a.y + cq.y);
      float2 Bv = make_float2(a.x - cq.x, a.y - cq.y);
      float2 Cv = make_float2(bq.x + d.x, bq.y + d.y);
      float2 D = make_float2(bq.x - d.x, bq.y - d.y);
      z0 = make_float2(A.x + Cv.x, A.y + Cv.y);
      z1 = make_float2(Bv.x + D.y, Bv.y - D.x);
      z2 = make_float2(A.x - Cv.x, A.y - Cv.y);
      z3 = make_float2(Bv.x - D.y, Bv.y + D.x);
    }

    // ---- extract: x[2m]=Re z[m], x[2m+1]=-Im z[m]; m = mb + 256q
    float e0 = z0.x * wv0.x, o0 = -z0.y * wv0.y;
    float e1 = z1.x * wv1.x, o1 = -z1.y * wv1.y;
    float e2 = z2.x * wv2.x, o2 = -z2.y * wv2.y;
    float e3 = z3.x * wv3.x, o3 = -z3.y * wv3.y;
    if (f >= 4 * c) {
      float2* ob2 = (float2*)(out + (size_t)b * NSAMP + (size_t)f * 1024);
      ob2[mb]       = make_float2(e0 + carE0, o0 + carO0);
      ob2[mb + 256] = make_float2(e1 + carE1, o1 + carO1);
    }
    carE0 = e2; carO0 = o2;
    carE1 = e3; carO1 = o3;
  }
}

// ---------------------------------------------------------------- launch
extern "C" void kernel_launch(void* const* d_in, const int* in_sizes, int n_in,
                              void* d_out, int out_size, void* d_ws, size_t ws_size,
                              hipStream_t stream) {
  const float* z    = (const float*)d_in[0];
  const float* imp  = (const float*)d_in[1];
  const float* W    = (const float*)d_in[2];
  const float* bias = (const float*)d_in[3];

  float* ws = (float*)d_ws;
  float*  tf   = ws + TF_OFF;
  float*  tft  = ws + TFT_OFF;
  float2* cur  = (float2*)(ws + CUR_OFF);
  float2* ckp  = (float2*)(ws + CK_OFF);
  float*  winT = ws + WINT_OFF;
  float2* twG  = (float2*)(ws + TW_OFF);
  float*  out  = (float*)d_out;

  init_tables<<<8, 256, 0, stream>>>(winT, twG);
  tf_gemm_mfma<<<COLS / 128, 256, 0, stream>>>(z, W, bias, tf);
  fwd_fft_kernel<<<NB * 4, 256, 0, stream>>>(imp, winT, twG, cur);
  recur_ck_t<<<(NB * NCOEF + 255) / 256, 256, 0, stream>>>(tf, cur, ckp, tft);
  fused_resyn<<<NB * NCHUNK, 256, 0, stream>>>(tft, cur, ckp, winT, twG, out);
}